// Round 11
// baseline (232.834 us; speedup 1.0000x reference)
//
#include <hip/hip_runtime.h>
#include <math.h>

// SSIM loss fp32, B=64 H=W=512, 11x11 Gaussian sigma=1.5, separable (w ⊗ w).
// R19 = R18 + taller tile (TSY 32->64) + 4-row stage-3.
// R18 post-mortem: VALUBusy*dur ~= 53us constant across R10/R13/R18 -> pure
// VALU work; occupancy 42->71% bought only 9% -> residency not binding.
// LDS model: stage-3 re-read 6 b128/px was 50% of LDS-pipe cycles. R19:
//  - TSY=64/HR=74, stage-3 thread does 4 rows x 2 cols: 4q x 7 b128 per 8 px
//    = 3.5/px (-42% dominant LDS term; total LDS cy/px -31%).
//  - h-conv halo overhead 74/64 vs 42/32 (-12% h-conv VALU); staging -11%.
//  - union raw(28.4KB)/hst(37.9KB) -> 37.9KB -> 4 blocks/CU (16 waves).
//  - stage-2 296 tasks: tid<40 takes a 2nd task (rows 64..73), both computed
//    before the overwrite barrier (dual acc; only wave 0 runs body twice).
// Conflict counter note: 22.9M invariant across 3 layouts, audits show <=2-way
// on all hot paths -> counter counts free 2-way aliasing (m136); ignored.

typedef float v2f __attribute__((ext_vector_type(2)));

#define TSY  64                  // output rows per block
#define HR   74                  // h-rows = TSY + 10
#define RAWS 48                  // raw row stride floats (16 mod 32)
#define GX   16
#define GY   8
#define NPART (64 * GY * GX)     // 8192

struct W11 { float w[11]; };

__global__ __launch_bounds__(256, 4) void ssim_main(
    const float* __restrict__ x, const float* __restrict__ y,
    float* __restrict__ partial, W11 wk, int atomic_mode)
{
    // union: phase A raw[2][74][48] = 7104 floats (28,416B), x at 0, y at 3552;
    //        phase B hst v2f[4][16][74] = 4736 v2f (37,888B).
    __shared__ __align__(16) float lds[9472];
    __shared__ float red[4];

    const int tid = threadIdx.x;
    // XCD-chunked bijective swizzle: 8192 blocks = 8 x 1024.
    const int lin = (int)blockIdx.x + GX * ((int)blockIdx.y + GY * (int)blockIdx.z);
    const int swz = ((lin & 7) << 10) | (lin >> 3);
    const int bx = swz & 15, by = (swz >> 4) & 7, bz = swz >> 7;
    const float* __restrict__ xb = x + (size_t)bz * (512 * 512);
    const float* __restrict__ yb = y + (size_t)bz * (512 * 512);
    const int ox = bx * 32;
    const int oy = by * TSY;

    // ---- stage 1: coalesced global -> LDS raw staging (zero-padded) ----
    // 1776 f4 tasks = 2 arrays x 74 rows x 12 f4; dst flat-contiguous.
    #pragma unroll
    for (int it = 0; it < 7; ++it) {
        const int i = tid + (it << 8);
        if (i < 1776) {
            const int a   = (i >= 888) ? 1 : 0;
            const int j   = i - a * 888;
            const int row = j / 12;          // 0..73
            const int f4c = j - row * 12;    // 0..11
            const int gr  = oy - 5 + row;
            const int gc  = ox - 8 + (f4c << 2);
            const float* __restrict__ sb = a ? yb : xb;
            float4 v = {0.f, 0.f, 0.f, 0.f};
            if ((unsigned)gr < 512u) {
                const float* __restrict__ rp = sb + gr * 512;
                if ((unsigned)gc <= 508u) {  // uniform-true for bx 1..14
                    v = *(const float4*)(rp + gc);
                } else {
                    float e[4];
                    #pragma unroll
                    for (int t = 0; t < 4; ++t) {
                        const int c = gc + t;
                        e[t] = ((unsigned)c < 512u) ? rp[c] : 0.f;
                    }
                    v = make_float4(e[0], e[1], e[2], e[3]);
                }
            }
            ((float4*)lds)[i] = v;
        }
    }
    __syncthreads();

    // ---- stage 2a: horizontal convs -> registers ----
    // 296 tasks = 74 rows x 4 col-groups; task (r,g): out col pairs
    // c = 4g+oc (lanes = cols c, c+16), reading raw f4 g..g+8 of row r.
#define HCONV(T, ACC)                                                        \
    {                                                                        \
        const int r_ = (T) >> 2;                                             \
        const int g_ = (T) & 3;                                              \
        const float4* __restrict__ px = (const float4*)(lds + r_ * RAWS + (g_ << 2)); \
        const float4* __restrict__ py = (const float4*)(lds + 3552 + r_ * RAWS + (g_ << 2)); \
        float4 X[9], Y[9];                                                   \
        _Pragma("unroll")                                                    \
        for (int k = 0; k < 9; ++k) X[k] = px[k];                            \
        _Pragma("unroll")                                                    \
        for (int k = 0; k < 9; ++k) Y[k] = py[k];                            \
        float fx[36], fy[36];                                                \
        _Pragma("unroll")                                                    \
        for (int k = 0; k < 9; ++k) {                                        \
            fx[4*k+0] = X[k].x; fx[4*k+1] = X[k].y;                          \
            fx[4*k+2] = X[k].z; fx[4*k+3] = X[k].w;                          \
            fy[4*k+0] = Y[k].x; fy[4*k+1] = Y[k].y;                          \
            fy[4*k+2] = Y[k].z; fy[4*k+3] = Y[k].w;                          \
        }                                                                    \
        _Pragma("unroll")                                                    \
        for (int q = 0; q < 4; ++q)                                          \
            _Pragma("unroll")                                                \
            for (int oc = 0; oc < 4; ++oc) ACC[q][oc] = (v2f)0.f;            \
        _Pragma("unroll")                                                    \
        for (int k = 0; k < 14; ++k) {                                       \
            const v2f xv = (v2f){fx[3 + k], fx[19 + k]};                     \
            const v2f yv = (v2f){fy[3 + k], fy[19 + k]};                     \
            const v2f ss = xv * xv + yv * yv;                                \
            const v2f xy = xv * yv;                                          \
            _Pragma("unroll")                                                \
            for (int oc = 0; oc < 4; ++oc) {                                 \
                const int j = k - oc;            /* compile-time */          \
                if (j < 0 || j > 10) continue;                               \
                const float wj = wk.w[j];                                    \
                ACC[0][oc] += wj * xv;                                       \
                ACC[1][oc] += wj * yv;                                       \
                ACC[2][oc] += wj * ss;                                       \
                ACC[3][oc] += wj * xy;                                       \
            }                                                                \
        }                                                                    \
    }

    v2f accA[4][4], accB[4][4];
    HCONV(tid, accA)
    const bool hasB = (tid < 40);
    if (hasB) { HCONV(256 + tid, accB) }
    __syncthreads();   // all raw reads done -> safe to overwrite with hst

    // ---- stage 2b: write h-conv results over the raw region ----
    // hst v2f layout: [q*1184 + c*74 + r].
    {
        v2f* __restrict__ hst = (v2f*)lds;
        const int rA = tid >> 2, gA = tid & 3;
        #pragma unroll
        for (int q = 0; q < 4; ++q)
            #pragma unroll
            for (int oc = 0; oc < 4; ++oc)
                hst[q * 1184 + (((gA << 2) + oc)) * HR + rA] = accA[q][oc];
        if (hasB) {
            const int t2 = 256 + tid;
            const int rB = t2 >> 2, gB = t2 & 3;
            #pragma unroll
            for (int q = 0; q < 4; ++q)
                #pragma unroll
                for (int oc = 0; oc < 4; ++oc)
                    hst[q * 1184 + (((gB << 2) + oc)) * HR + rB] = accB[q][oc];
        }
    }
    __syncthreads();
#undef HCONV

    // ---- stage 3: vertical convs + SSIM; 256 threads = 16 cp x 16 row-quads
    // b128 starts (148*cp + 8*quad) mod 32 cover all 32 banks per 8 lanes.
    const int cp = tid & 15;
    const int m0 = (tid >> 4) << 2;              // output rows m0..m0+3
    float lsum = 0.f;
    {
        const v2f* __restrict__ hst = (const v2f*)lds;
        v2f s[4][4];
        #pragma unroll
        for (int q = 0; q < 4; ++q) {
            const float4* __restrict__ p4 = (const float4*)(hst + q * 1184 + cp * HR + m0);
            float4 Q[7];
            #pragma unroll
            for (int k = 0; k < 7; ++k) Q[k] = p4[k];   // h-rows m0..m0+13
            #pragma unroll
            for (int o = 0; o < 4; ++o) {
                v2f a = (v2f)0.f;
                #pragma unroll
                for (int j = 0; j < 11; ++j) {
                    const int t = o + j;                 // 0..13 compile-time
                    const v2f rv = (t & 1) ? (v2f){Q[t >> 1].z, Q[t >> 1].w}
                                           : (v2f){Q[t >> 1].x, Q[t >> 1].y};
                    a += wk.w[j] * rv;
                }
                s[q][o] = a;
            }
        }

        const float C1 = 1e-4f, C2 = 9e-4f;
        #pragma unroll
        for (int o = 0; o < 4; ++o) {
            const v2f mx = s[0][o], my = s[1][o];
            const v2f mx2 = mx * mx, my2 = my * my, mxy = mx * my;
            const v2f sig_sum = s[2][o] - mx2 - my2;   // sigma_x2 + sigma_y2
            const v2f sig_xy  = s[3][o] - mxy;
            const v2f num = (2.f * mxy + C1) * (2.f * sig_xy + C2);
            const v2f den = (mx2 + my2 + C1) * (sig_sum + C2) + 1e-12f;
            lsum += num.x * __builtin_amdgcn_rcpf(den.x)
                  + num.y * __builtin_amdgcn_rcpf(den.y);
        }
    }

    // ---- block reduction (4 waves) ----
    #pragma unroll
    for (int off = 32; off; off >>= 1) lsum += __shfl_down(lsum, off);
    if ((tid & 63) == 0) red[tid >> 6] = lsum;
    __syncthreads();
    if (tid == 0) {
        const float v = red[0] + red[1] + red[2] + red[3];
        if (atomic_mode) atomicAdd(partial, v);
        else partial[(bz * GY + by) * GX + bx] = v;
    }
}

__global__ __launch_bounds__(1024) void ssim_fin(const float* __restrict__ partial,
                                                 float* __restrict__ out, int n)
{
    float s = 0.f;
    for (int i = threadIdx.x; i < n; i += 1024) s += partial[i];
    #pragma unroll
    for (int off = 32; off; off >>= 1) s += __shfl_down(s, off);
    __shared__ float red[16];
    if ((threadIdx.x & 63) == 0) red[threadIdx.x >> 6] = s;
    __syncthreads();
    if (threadIdx.x == 0) {
        float v = 0.f;
        #pragma unroll
        for (int i = 0; i < 16; ++i) v += red[i];
        out[0] = 1.0f - v * (1.0f / 16777216.0f);
    }
}

extern "C" void kernel_launch(void* const* d_in, const int* in_sizes, int n_in,
                              void* d_out, int out_size, void* d_ws, size_t ws_size,
                              hipStream_t stream) {
    const float* x = (const float*)d_in[0];
    const float* y = (const float*)d_in[1];
    float* out = (float*)d_out;
    float* ws  = (float*)d_ws;

    W11 wk;
    double e[11], s = 0.0;
    for (int i = 0; i < 11; ++i) {
        double d = (double)i - 5.0;
        e[i] = exp(-(d * d) / 4.5);
        s += e[i];
    }
    for (int i = 0; i < 11; ++i) wk.w[i] = (float)(e[i] / s);

    const bool use_partial = ws_size >= (size_t)NPART * sizeof(float);
    if (!use_partial) hipMemsetAsync(d_ws, 0, sizeof(float), stream);

    hipLaunchKernelGGL(ssim_main, dim3(GX, GY, 64), dim3(256), 0, stream,
                       x, y, ws, wk, use_partial ? 0 : 1);
    hipLaunchKernelGGL(ssim_fin, dim3(1), dim3(1024), 0, stream,
                       ws, out, use_partial ? NPART : 1);
}